// Round 7
// baseline (238.997 us; speedup 1.0000x reference)
//
#include <hip/hip_runtime.h>
#include <hip/hip_bf16.h>

// Problem dims (fixed by reference setup_inputs)
#define M_DIM 32
#define K_DIM 8192
#define N_DIM 8192
#define KS 2                         // k halves (per-block k-split)
#define KHALF (K_DIM / KS)           // 4096 k per block
#define NRPB 16                      // full qweight rows per block
#define MAIN_BLOCKS ((N_DIM / NRPB) * KS)  // 1024; 4 blk/CU -> all co-resident

#define QW_ROWI4 (K_DIM / 8)         // 1024 int4 per qweight row
#define SC_ROW (K_DIM / 16)          // 512 f32 per scales row

typedef _Float16 half8   __attribute__((ext_vector_type(8)));
typedef _Float16 half2_t __attribute__((ext_vector_type(2)));
typedef float    floatx4 __attribute__((ext_vector_type(4)));

// ---- Proven E2M1 bit-decode (R1/R6 pedigree, absmax 2.0) ----
// One byte = 2 fp4 (low nibble = even k). mag code m -> f16 bits t<<9,
// t = min(28m, m+28); sign bit3 -> bit15.
__device__ __forceinline__ uint32_t dec2(uint32_t b) {
  uint32_t c0 = b & 0xFu, c1 = (b >> 4) & 0xFu;
  uint32_t m0 = c0 & 7u, m1 = c1 & 7u;
  uint32_t t0 = min(28u * m0, m0 + 28u);
  uint32_t t1 = min(28u * m1, m1 + 28u);
  return (t0 << 9) | ((c0 & 8u) << 12)
       | (t1 << 25) | ((c1 & 8u) << 28);
}

// Packed dword (4 payload bytes = 8 fp4 along k) -> 8 f16, times f16 scale.
__device__ __forceinline__ half8 decode8p(uint32_t q, _Float16 s) {
  union { uint32_t u[4]; half8 h; } w;
  w.u[0] = dec2(q & 0xFFu);
  w.u[1] = dec2((q >> 8) & 0xFFu);
  w.u[2] = dec2((q >> 16) & 0xFFu);
  w.u[3] = dec2((q >> 24) & 0xFFu);
  half8 sv = {s, s, s, s, s, s, s, s};
  return w.h * sv;
}

typedef _Float16 half4_t __attribute__((ext_vector_type(4)));

// inp f32 -> ws f16 (once; 512 KB)
__global__ void convertA_kernel(const floatx4* __restrict__ in4,
                                half4_t* __restrict__ out4) {
  int idx = blockIdx.x * blockDim.x + threadIdx.x;
  floatx4 f = in4[idx];
  half4_t h;
  h[0] = (_Float16)f[0]; h[1] = (_Float16)f[1];
  h[2] = (_Float16)f[2]; h[3] = (_Float16)f[3];
  out4[idx] = h;
}

// out = bias + part[0] + part[1]
__global__ void reduce_kernel(const floatx4* __restrict__ part,
                              const floatx4* __restrict__ bias4,
                              floatx4* __restrict__ out4) {
  int idx = blockIdx.x * blockDim.x + threadIdx.x;   // [0, 65536)
  out4[idx] = bias4[idx & (N_DIM / 4 - 1)]
            + part[idx] + part[(M_DIM * N_DIM / 4) + idx];
}

__global__ __launch_bounds__(256, 4) void fp4_linear_kernel(
    const int4*     __restrict__ qw4,     // [N][1024] int4 view of [N, K/2] i32
    const float*    __restrict__ scales,  // [8192, 512] f32
    const float*    __restrict__ amaxp,   // [1]
    const _Float16* __restrict__ Af16,    // [32, 8192] f16 (ws)
    float*          __restrict__ part)    // [2][32][8192] f32 partials
{
  // XOR-swizzled LDS, no pads: exactly 40960 B -> 4 blocks/CU.
  __shared__ uint32_t Qs[NRPB * 512];     // 32768 B: packed nibbles, [row][512]
  __shared__ _Float16 Ss[NRPB * 256];     //  8192 B: scales*amax f16, [row][256]

  const int t    = threadIdx.x;
  const int lane = t & 63;
  const int w    = t >> 6;                // wave id = k-quarter of the half
  const int ks   = blockIdx.x & 1;        // which K half
  const int g    = blockIdx.x >> 1;       // row group [0,512)
  const int n0   = g * NRPB;
  const float amax = amaxp[0];

  // ---- Stage Q: 16 rows x 8 KB CONTIGUOUS each (block total 128 KB). ----
  // Each wave-instr reads 1 KB contiguous within one row; per-thread 32 int4
  // in 4 batches of 8 (bounded regs, deep burst). Pack 4 int32 -> 1 dword.
  {
    const int4* src = qw4 + (size_t)ks * (KHALF / 8);  // +512 int4 row offset
    for (int gq = 0; gq < 4; ++gq) {
      int4 tmp[8];
#pragma unroll
      for (int j = 0; j < 8; ++j) {
        const int flat = (gq * 8 + j) * 256 + t;   // [0, 8192)
        const int r = flat >> 9, col = flat & 511;
        tmp[j] = src[(size_t)(n0 + r) * QW_ROWI4 + col];
      }
#pragma unroll
      for (int j = 0; j < 8; ++j) {
        const int flat = (gq * 8 + j) * 256 + t;
        const int r = flat >> 9, col = flat & 511;
        uint32_t pk = ((uint32_t)tmp[j].x & 0xFFu)
                    | (((uint32_t)tmp[j].y & 0xFFu) << 8)
                    | (((uint32_t)tmp[j].z & 0xFFu) << 16)
                    | (((uint32_t)tmp[j].w & 0xFFu) << 24);
        Qs[r * 512 + (col ^ r)] = pk;              // XOR swizzle: 2-way banks
      }
    }
  }

  // ---- Stage S: 16 rows x 1 KB contiguous (16 KB) -> f16 * amax. ----
  {
#pragma unroll
    for (int j = 0; j < 4; ++j) {
      const int flat = j * 256 + t;                // [0, 1024) float4
      const int r = flat >> 6, c4 = flat & 63;
      floatx4 f = reinterpret_cast<const floatx4*>(
          scales + (size_t)(n0 + r) * SC_ROW + ks * (KHALF / 16))[c4];
#pragma unroll
      for (int i = 0; i < 2; ++i) {                // pair-swizzled half2 writes
        const int p = c4 * 2 + i;                  // pair index [0,128)
        half2_t h2 = {(_Float16)(f[2 * i] * amax),
                      (_Float16)(f[2 * i + 1] * amax)};
        *(half2_t*)&Ss[r * 256 + (p ^ r) * 2] = h2;
      }
    }
  }
  __syncthreads();

  // ---- Compute: wave w covers k in [w*1024, w*1024+1024): 32 steps x 2 MFMA.
  const int row  = lane & 15;   // n-local (B) / m-local (A)
  const int quad = lane >> 4;
  const uint32_t* qrow = &Qs[row * 512];
  const _Float16* srow = &Ss[row * 256];
  const _Float16* a0p = Af16 + (size_t)row * K_DIM + ks * KHALF + w * 1024;
  const _Float16* a1p = a0p + (size_t)16 * K_DIM;

  floatx4 acc0 = {0.f, 0.f, 0.f, 0.f};   // m 0..15
  floatx4 acc1 = {0.f, 0.f, 0.f, 0.f};   // m 16..31

#pragma unroll 4
  for (int it = 0; it < 32; ++it) {
    const uint32_t q = qrow[(w * 128 + it * 4 + quad) ^ row];
    const _Float16 s = srow[(((w * 32 + it) ^ row) * 2) + (quad >> 1)];
    half8 b  = decode8p(q, s);
    half8 a0 = *(const half8*)(a0p + it * 32 + quad * 8);
    half8 a1 = *(const half8*)(a1p + it * 32 + quad * 8);
    acc0 = __builtin_amdgcn_mfma_f32_16x16x32_f16(a0, b, acc0, 0, 0, 0);
    acc1 = __builtin_amdgcn_mfma_f32_16x16x32_f16(a1, b, acc1, 0, 0, 0);
  }

  // ---- Cross-wave (4 k-quarter) LDS reduce, then plain partial store. ----
  // D layout: col(n) = lane&15, row(m) = quad*4 + reg (verified R1..R6).
  __syncthreads();                         // Qs consumed; reuse as scratch
  float* red = (float*)Qs;                 // [4][32][18] = 9216 B
  {
    float* slab = red + w * (32 * 18);
#pragma unroll
    for (int r4 = 0; r4 < 4; ++r4) {
      const int m = quad * 4 + r4;
      slab[m * 18 + row]        = acc0[r4];
      slab[(m + 16) * 18 + row] = acc1[r4];
    }
  }
  __syncthreads();
  float* pb = part + (size_t)ks * (M_DIM * N_DIM);
#pragma unroll
  for (int i = 0; i < 2; ++i) {
    const int o = i * 256 + t;             // [0, 512) outputs
    const int m = o >> 4, n = o & 15;
    float v = red[m * 18 + n] + red[576 + m * 18 + n]
            + red[2 * 576 + m * 18 + n] + red[3 * 576 + m * 18 + n];
    pb[(size_t)m * N_DIM + n0 + n] = v;
  }
}

extern "C" void kernel_launch(void* const* d_in, const int* in_sizes, int n_in,
                              void* d_out, int out_size, void* d_ws, size_t ws_size,
                              hipStream_t stream) {
  const float* inp    = (const float*)d_in[0];
  const int4*  qw4    = (const int4*)d_in[1];
  const float* scales = (const float*)d_in[2];
  const float* amaxp  = (const float*)d_in[3];
  const float* bias   = (const float*)d_in[4];
  float* out = (float*)d_out;

  // ws: [0, 512KB) A f16; [512KB, 512KB+2MB) partial slabs
  _Float16* Af16 = (_Float16*)d_ws;
  float*    part = (float*)((char*)d_ws + (size_t)M_DIM * K_DIM * sizeof(_Float16));

  convertA_kernel<<<M_DIM * K_DIM / 4 / 256, 256, 0, stream>>>(
      (const floatx4*)inp, (half4_t*)Af16);
  fp4_linear_kernel<<<MAIN_BLOCKS, 256, 0, stream>>>(
      qw4, scales, amaxp, Af16, part);
  reduce_kernel<<<M_DIM * N_DIM / 4 / 256, 256, 0, stream>>>(
      (const floatx4*)part, (const floatx4*)bias, (floatx4*)out);
}

// Round 8
// 219.294 us; speedup vs baseline: 1.0898x; 1.0898x over previous
//
#include <hip/hip_runtime.h>
#include <hip/hip_bf16.h>

// Problem dims (fixed by reference setup_inputs)
#define M_DIM 32
#define K_DIM 8192
#define N_DIM 8192
#define KS 16                        // k-split slices
#define KCH (K_DIM / KS)             // 512 k per block
#define CHK 128                      // k per pipelined chunk
#define NCHK (KCH / CHK)             // 4 chunks
#define STEPS (CHK / 32)             // 4 MFMA k-steps per chunk
#define NPB 128                      // n-cols per block
#define MAIN_BLOCKS ((N_DIM / NPB) * KS)  // 1024

#define QW_ROWI4 (K_DIM / 8)         // 1024 int4 per qweight row
#define SC_ROW (K_DIM / 16)          // 512 f32 per scales row

// LDS strides (R6-proven padding class; conflicts measured negligible)
#define QROW 17                      // packed dwords per Q row (16 + 1)
#define AROW 136                     // f16 per A row (128 + 8)
#define SROW 9                       // f32 per S row (8 + 1)

typedef _Float16 half8   __attribute__((ext_vector_type(8)));
typedef _Float16 half4_t __attribute__((ext_vector_type(4)));
typedef float    floatx4 __attribute__((ext_vector_type(4)));

// ---- Proven E2M1 bit-decode (R1/R6 pedigree, absmax 2.0) ----
__device__ __forceinline__ uint32_t dec2(uint32_t b) {
  uint32_t c0 = b & 0xFu, c1 = (b >> 4) & 0xFu;
  uint32_t m0 = c0 & 7u, m1 = c1 & 7u;
  uint32_t t0 = min(28u * m0, m0 + 28u);
  uint32_t t1 = min(28u * m1, m1 + 28u);
  return (t0 << 9) | ((c0 & 8u) << 12)
       | (t1 << 25) | ((c1 & 8u) << 28);
}

// Packed dword (4 payload bytes = 8 fp4 along k) -> 8 f16, times f16 scale.
__device__ __forceinline__ half8 decode8p(uint32_t q, _Float16 s) {
  union { uint32_t u[4]; half8 h; } w;
  w.u[0] = dec2(q & 0xFFu);
  w.u[1] = dec2((q >> 8) & 0xFFu);
  w.u[2] = dec2((q >> 16) & 0xFFu);
  w.u[3] = dec2((q >> 24) & 0xFFu);
  half8 sv = {s, s, s, s, s, s, s, s};
  return w.h * sv;
}

// inp f32 -> ws f16 (1 MB -> 512 KB, once)
__global__ void convertA_kernel(const floatx4* __restrict__ in4,
                                half4_t* __restrict__ out4) {
  int idx = blockIdx.x * blockDim.x + threadIdx.x;
  floatx4 f = in4[idx];
  half4_t h;
  h[0] = (_Float16)f[0]; h[1] = (_Float16)f[1];
  h[2] = (_Float16)f[2]; h[3] = (_Float16)f[3];
  out4[idx] = h;
}

// out = bias + sum of KS partial slabs
__global__ void reduce_kernel(const floatx4* __restrict__ part,
                              const floatx4* __restrict__ bias4,
                              floatx4* __restrict__ out4) {
  int idx = blockIdx.x * blockDim.x + threadIdx.x;   // [0, 65536)
  floatx4 acc = bias4[idx & (N_DIM / 4 - 1)];
#pragma unroll
  for (int s = 0; s < KS; ++s)
    acc += part[(size_t)s * (M_DIM * N_DIM / 4) + idx];
  out4[idx] = acc;
}

template <bool F16A>
__global__ __launch_bounds__(256, 4) void fp4_linear_kernel(
    const void*  __restrict__ Av,      // f16 [32][8192] (ws) or f32 (inp)
    const int4*  __restrict__ qw4,     // [N][1024] int4 view of [N, K/2] i32
    const float* __restrict__ scales,  // [8192, 512] f32
    const float* __restrict__ amaxp,   // [1]
    float*       __restrict__ part)    // [KS][32][8192] f32 partial slabs
{
  __shared__ uint32_t Qs[NPB * QROW];     // 8704 B (packed nibbles)
  __shared__ _Float16 As[M_DIM * AROW];   // 8704 B
  __shared__ float    Ss[NPB * SROW];     // 4608 B   -> 22016 B total

  const int t    = threadIdx.x;
  const int lane = t & 63;
  const int w    = t >> 6;
  const int ks   = blockIdx.x & (KS - 1);
  const int nb   = blockIdx.x >> 4;       // log2(KS)
  const int n0   = nb * NPB;
  const int kb   = ks * KCH;
  const float amax = amaxp[0];

  // Per-thread staging geometry (fixed across chunks)
  const int qr = t >> 4, qc = t & 15;       // Q: 16 rows x 16 int4 per j-step
  const int4* qsrc = qw4 + (size_t)(n0 + qr) * QW_ROWI4 + ks * (KCH / 8) + qc;
  const int sr = t >> 1, sh = t & 1;        // S: 128 rows x 2 float4
  const float* ssrc = scales + (size_t)(n0 + sr) * SC_ROW + ks * (KCH / 16) + sh * 4;
  // A f16: 32 rows x 16 half8 per chunk (2 j-steps); f32: 32 rows x 32 float4 (4 j-steps)
  const int ar16 = t >> 4, ac16 = t & 15;
  const _Float16* asrc16 =
      (const _Float16*)Av + (size_t)ar16 * K_DIM + kb + ac16 * 8;
  const int ar32 = t >> 5, ac32 = t & 31;
  const float* asrc32 = (const float*)Av + (size_t)ar32 * K_DIM + kb + ac32 * 4;

  // Staging registers (const-indexed, fully unrolled -> no scratch)
  int4    qreg[8];
  half8   areg16[2];
  floatx4 areg32[4];
  floatx4 sreg;

  // ---------------- preload chunk 0 ----------------
  {
#pragma unroll
    for (int j = 0; j < 8; ++j)
      qreg[j] = qsrc[(size_t)j * 16 * QW_ROWI4];
    if (F16A) {
#pragma unroll
      for (int j = 0; j < 2; ++j)
        areg16[j] = *(const half8*)(asrc16 + (size_t)j * 16 * K_DIM);
    } else {
#pragma unroll
      for (int j = 0; j < 4; ++j)
        areg32[j] = *(const floatx4*)(asrc32 + (size_t)j * 8 * K_DIM);
    }
    sreg = *(const floatx4*)ssrc;
  }

  // Compute-side pointers
  const int row  = lane & 15;
  const int quad = lane >> 4;
  const int nloc = w * 32;
  const uint32_t* qAp = &Qs[(nloc + row) * QROW];
  const uint32_t* qBp = &Qs[(nloc + 16 + row) * QROW];
  const _Float16* a0p = &As[row * AROW];
  const _Float16* a1p = &As[(row + 16) * AROW];
  const float*    sAp = &Ss[(nloc + row) * SROW];
  const float*    sBp = &Ss[(nloc + 16 + row) * SROW];

  floatx4 acc00 = {0.f, 0.f, 0.f, 0.f};
  floatx4 acc01 = {0.f, 0.f, 0.f, 0.f};
  floatx4 acc10 = {0.f, 0.f, 0.f, 0.f};
  floatx4 acc11 = {0.f, 0.f, 0.f, 0.f};

  for (int c = 0; c < NCHK; ++c) {
    if (c) __syncthreads();              // previous chunk's LDS fully consumed

    // -------- store staged regs -> LDS --------
#pragma unroll
    for (int j = 0; j < 8; ++j) {
      uint32_t pk = ((uint32_t)qreg[j].x & 0xFFu)
                  | (((uint32_t)qreg[j].y & 0xFFu) << 8)
                  | (((uint32_t)qreg[j].z & 0xFFu) << 16)
                  | (((uint32_t)qreg[j].w & 0xFFu) << 24);
      Qs[(j * 16 + qr) * QROW + qc] = pk;
    }
    if (F16A) {
#pragma unroll
      for (int j = 0; j < 2; ++j)
        *(half8*)&As[(j * 16 + ar16) * AROW + ac16 * 8] = areg16[j];
    } else {
#pragma unroll
      for (int j = 0; j < 4; ++j) {
        floatx4 f = areg32[j];
        half4_t h;
        h[0] = (_Float16)f[0]; h[1] = (_Float16)f[1];
        h[2] = (_Float16)f[2]; h[3] = (_Float16)f[3];
        *(half4_t*)&As[(j * 8 + ar32) * AROW + ac32 * 4] = h;
      }
    }
    {
      float* sd = &Ss[sr * SROW + sh * 4];
      sd[0] = sreg[0] * amax; sd[1] = sreg[1] * amax;
      sd[2] = sreg[2] * amax; sd[3] = sreg[3] * amax;
    }
    __syncthreads();

    // -------- issue next chunk's loads (in flight during compute) --------
    if (c + 1 < NCHK) {
      const int co = c + 1;
#pragma unroll
      for (int j = 0; j < 8; ++j)
        qreg[j] = qsrc[(size_t)j * 16 * QW_ROWI4 + co * (CHK / 8)];
      if (F16A) {
#pragma unroll
        for (int j = 0; j < 2; ++j)
          areg16[j] = *(const half8*)(asrc16 + (size_t)j * 16 * K_DIM + co * CHK);
      } else {
#pragma unroll
        for (int j = 0; j < 4; ++j)
          areg32[j] = *(const floatx4*)(asrc32 + (size_t)j * 8 * K_DIM + co * CHK);
      }
      sreg = *(const floatx4*)(ssrc + co * (CHK / 16));
    }

    // -------- compute chunk c from LDS --------
#pragma unroll
    for (int it = 0; it < STEPS; ++it) {
      const uint32_t qA = qAp[it * 4 + quad];
      const uint32_t qB = qBp[it * 4 + quad];
      const _Float16 sA = (_Float16)sAp[it * 2 + (quad >> 1)];
      const _Float16 sB = (_Float16)sBp[it * 2 + (quad >> 1)];
      half8 bA = decode8p(qA, sA);
      half8 bB = decode8p(qB, sB);
      half8 a0 = *(const half8*)(a0p + it * 32 + quad * 8);
      half8 a1 = *(const half8*)(a1p + it * 32 + quad * 8);
      acc00 = __builtin_amdgcn_mfma_f32_16x16x32_f16(a0, bA, acc00, 0, 0, 0);
      acc01 = __builtin_amdgcn_mfma_f32_16x16x32_f16(a0, bB, acc01, 0, 0, 0);
      acc10 = __builtin_amdgcn_mfma_f32_16x16x32_f16(a1, bA, acc10, 0, 0, 0);
      acc11 = __builtin_amdgcn_mfma_f32_16x16x32_f16(a1, bB, acc11, 0, 0, 0);
    }
  }

  // ---- Epilogue: partial slab store. D: col(n)=lane&15, row(m)=quad*4+reg. ----
  float* pb = part + (size_t)ks * (M_DIM * N_DIM);
#pragma unroll
  for (int r = 0; r < 4; ++r) {
    const int m = quad * 4 + r;
    float* o0 = pb + (size_t)m * N_DIM + n0 + nloc;
    float* o1 = pb + (size_t)(m + 16) * N_DIM + n0 + nloc;
    o0[row]      = acc00[r];
    o0[16 + row] = acc01[r];
    o1[row]      = acc10[r];
    o1[16 + row] = acc11[r];
  }
}

extern "C" void kernel_launch(void* const* d_in, const int* in_sizes, int n_in,
                              void* d_out, int out_size, void* d_ws, size_t ws_size,
                              hipStream_t stream) {
  const float* inp    = (const float*)d_in[0];
  const int4*  qw4    = (const int4*)d_in[1];
  const float* scales = (const float*)d_in[2];
  const float* amaxp  = (const float*)d_in[3];
  const float* bias   = (const float*)d_in[4];
  float* out = (float*)d_out;

  const size_t part_bytes = (size_t)KS * M_DIM * N_DIM * sizeof(float);  // 16.8 MB
  const size_t a16_bytes  = (size_t)M_DIM * K_DIM * sizeof(_Float16);    // 512 KB
  float* partp = (float*)d_ws;                       // partials first

  if (ws_size >= part_bytes + a16_bytes) {
    _Float16* Af16 = (_Float16*)((char*)d_ws + part_bytes);
    convertA_kernel<<<M_DIM * K_DIM / 4 / 256, 256, 0, stream>>>(
        (const floatx4*)inp, (half4_t*)Af16);
    fp4_linear_kernel<true><<<MAIN_BLOCKS, 256, 0, stream>>>(
        Af16, qw4, scales, amaxp, partp);
  } else {
    fp4_linear_kernel<false><<<MAIN_BLOCKS, 256, 0, stream>>>(
        inp, qw4, scales, amaxp, partp);
  }
  reduce_kernel<<<M_DIM * N_DIM / 4 / 256, 256, 0, stream>>>(
      (const floatx4*)partp, (const floatx4*)bias, (floatx4*)out);
}